// Round 1
// baseline (2724.262 us; speedup 1.0000x reference)
//
#include <hip/hip_runtime.h>

// ---------------- constants ----------------
constexpr int B_ = 4, C_ = 96, H_ = 256, W_ = 256;
constexpr int NWIN = 32;                 // nh = nw
constexpr int NWINS = 4096;              // B*nh*nw
constexpr int NC_ = 6144;                // N*C
constexpr int PDIM_ = 30;
constexpr float EPSG = 1e-8f;
constexpr float ATT_Ac = 30.f, ATT_Bc = 20.f;
constexpr float QSCALE = 0.17677669529663687f;  // 32^-0.5
constexpr long long BIG = (long long)B_ * C_ * H_ * W_;  // 25165824

// ---------------- weight transpose for qkv ----------------
__global__ void k_wt(const float* __restrict__ lfqk_w, const float* __restrict__ lfqk_b,
                     const float* __restrict__ lfv_w, const float* __restrict__ lfv_b,
                     float* __restrict__ wt, float* __restrict__ bq) {
  int t = blockIdx.x * 256 + threadIdx.x;        // grid 108 blocks -> 27648 threads
  if (t < 96 * 288) {
    int ic = t / 288, oc = t % 288;
    wt[t] = (oc < 192) ? lfqk_w[oc * 96 + ic] : lfv_w[(oc - 192) * 96 + ic];
  }
  if (t < 288) bq[t] = (t < 192) ? lfqk_b[t] : lfv_b[t - 192];
}

// ---------------- relative-position bias MLP (3,64,64) ----------------
__global__ void k_bias(const float* __restrict__ w1, const float* __restrict__ b1,
                       const float* __restrict__ w2, const float* __restrict__ b2,
                       float* __restrict__ bias) {
  int t = blockIdx.x * 256 + threadIdx.x;
  if (t >= 4096) return;
  int n = t >> 6, m = t & 63;
  float dy = (float)((n >> 3) - (m >> 3));
  float dx = (float)((n & 7) - (m & 7));
  float fy = (dy > 0.f ? 1.f : (dy < 0.f ? -1.f : 0.f)) * log1pf(fabsf(dy));
  float fx = (dx > 0.f ? 1.f : (dx < 0.f ? -1.f : 0.f)) * log1pf(fabsf(dx));
  float o0 = b2[0], o1 = b2[1], o2 = b2[2];
  for (int j = 0; j < 256; ++j) {
    float h = fmaxf(w1[2 * j] * fy + w1[2 * j + 1] * fx + b1[j], 0.f);
    o0 += w2[j] * h; o1 += w2[256 + j] * h; o2 += w2[512 + j] * h;
  }
  bias[t] = o0; bias[4096 + t] = o1; bias[8192 + t] = o2;
}

// ---------------- qkv 1x1 conv into window layout ----------------
__global__ __launch_bounds__(256) void k_qkv(const float* __restrict__ X,
                      const float* __restrict__ wt, const float* __restrict__ bq,
                      float* __restrict__ q, float* __restrict__ k, float* __restrict__ v) {
  __shared__ float xw[96][64];
  int win = blockIdx.x;
  int b = win >> 10, wy = (win >> 5) & 31, wx = win & 31;
  int t = threadIdx.x;
  const float* Xb = X + (long long)b * 96 * 65536 + wy * 8 * 256 + wx * 8;
  for (int f = t; f < 6144; f += 256) {
    int ic = f >> 6, p = f & 63;
    xw[ic][p] = Xb[ic * 65536 + (p >> 3) * 256 + (p & 7)];
  }
  __syncthreads();
  int lane = t & 63, quad = t >> 6;
  int nbase = quad * 16;
  for (int ob = 0; ob < 288; ob += 64) {
    int oc = ob + lane;
    if (oc < 288) {
      float acc[16];
#pragma unroll
      for (int i = 0; i < 16; ++i) acc[i] = 0.f;
#pragma unroll 4
      for (int ic = 0; ic < 96; ++ic) {
        float wv = wt[ic * 288 + oc];
        const float4* xr = (const float4*)&xw[ic][nbase];
#pragma unroll
        for (int g = 0; g < 4; ++g) {
          float4 x = xr[g];
          acc[4 * g + 0] += wv * x.x; acc[4 * g + 1] += wv * x.y;
          acc[4 * g + 2] += wv * x.z; acc[4 * g + 3] += wv * x.w;
        }
      }
      float bb = bq[oc];
      int s = oc / 96, c = oc % 96;
      float scale = (s == 0) ? QSCALE : 1.f;
      float* dst = ((s == 0) ? q : (s == 1) ? k : v) + (long long)win * 6144 + c;
#pragma unroll
      for (int i = 0; i < 16; ++i) dst[(nbase + i) * 96] = (acc[i] + bb) * scale;
    }
  }
}

// ---------------- window attention: 1 block/window, wave h = head h ----------------
__global__ __launch_bounds__(192) void k_attn(const float* __restrict__ q, const float* __restrict__ kk_,
                       const float* __restrict__ v, const float* __restrict__ bias,
                       float* __restrict__ aw) {
  __shared__ float kl[3][64][32];
  __shared__ float vl[3][64][32];
  int win = blockIdx.x;
  int t = threadIdx.x;
  long long base = (long long)win * 6144;
  for (int f = t; f < 6144; f += 192) {
    int n = f / 96, c = f % 96, h = c >> 5, d = c & 31;
    kl[h][n][d] = kk_[base + f];
    vl[h][n][d] = v[base + f];
  }
  __syncthreads();
  int h = t >> 6, lane = t & 63;
  float qr[32];
  const float4* qp = (const float4*)(q + base + lane * 96 + h * 32);
#pragma unroll
  for (int i = 0; i < 8; ++i) {
    float4 x = qp[i];
    qr[4 * i] = x.x; qr[4 * i + 1] = x.y; qr[4 * i + 2] = x.z; qr[4 * i + 3] = x.w;
  }
  const float* bh = bias + h * 4096 + lane * 64;
  float s[64];
#pragma unroll
  for (int m = 0; m < 64; ++m) {
    float acc = 0.f;
    const float4* kp = (const float4*)kl[h][m];
#pragma unroll
    for (int i = 0; i < 8; ++i) {
      float4 x = kp[i];
      acc += qr[4 * i] * x.x + qr[4 * i + 1] * x.y + qr[4 * i + 2] * x.z + qr[4 * i + 3] * x.w;
    }
    s[m] = acc + bh[m];
  }
  float mx = -1e30f;
#pragma unroll
  for (int m = 0; m < 64; ++m) mx = fmaxf(mx, s[m]);
  float sum = 0.f;
#pragma unroll
  for (int m = 0; m < 64; ++m) { float p = __expf(s[m] - mx); s[m] = p; sum += p; }
  float inv = 1.f / sum;
  float o[32];
#pragma unroll
  for (int d = 0; d < 32; ++d) o[d] = 0.f;
#pragma unroll
  for (int m = 0; m < 64; ++m) {
    float p = s[m];
    const float4* vp = (const float4*)vl[h][m];
#pragma unroll
    for (int i = 0; i < 8; ++i) {
      float4 x = vp[i];
      o[4 * i] += p * x.x; o[4 * i + 1] += p * x.y; o[4 * i + 2] += p * x.z; o[4 * i + 3] += p * x.w;
    }
  }
  float4* op = (float4*)(aw + base + lane * 96 + h * 32);
#pragma unroll
  for (int i = 0; i < 8; ++i) {
    float4 x;
    x.x = o[4 * i] * inv; x.y = o[4 * i + 1] * inv; x.z = o[4 * i + 2] * inv; x.w = o[4 * i + 3] * inv;
    op[i] = x;
  }
}

// ---------------- src stats (two-stage reduction over x4 per batch) ----------------
__global__ void k_redA(const float* __restrict__ x4, float* __restrict__ part) {
  int b = blockIdx.x, blk = blockIdx.y, t = threadIdx.x;
  const float4* p = (const float4*)(x4 + (long long)b * 6291456 + (long long)blk * 49152);
  float s = 0.f, ss = 0.f;
  for (int i = t; i < 12288; i += 256) {
    float4 x = p[i];
    s += x.x + x.y + x.z + x.w;
    ss += x.x * x.x + x.y * x.y + x.z * x.z + x.w * x.w;
  }
  __shared__ float r1[256], r2[256];
  r1[t] = s; r2[t] = ss; __syncthreads();
  for (int st = 128; st; st >>= 1) {
    if (t < st) { r1[t] += r1[t + st]; r2[t] += r2[t + st]; }
    __syncthreads();
  }
  if (t == 0) { part[(b * 128 + blk) * 2] = r1[0]; part[(b * 128 + blk) * 2 + 1] = r2[0]; }
}

__global__ void k_redB(const float* __restrict__ part, float* __restrict__ stats) {
  int b = blockIdx.x, t = threadIdx.x;  // block 128
  float s = part[(b * 128 + t) * 2], ss = part[(b * 128 + t) * 2 + 1];
  __shared__ float r1[128], r2[128];
  r1[t] = s; r2[t] = ss; __syncthreads();
  for (int st = 64; st; st >>= 1) {
    if (t < st) { r1[t] += r1[t + st]; r2[t] += r2[t + st]; }
    __syncthreads();
  }
  if (t == 0) {
    float n = 6291456.f, m = r1[0] / n;
    stats[b] = m;
    stats[4 + b] = sqrtf(fmaxf(r2[0] / n - m * m, 0.f) + EPSG);
  }
}

// ---------------- patch-embed GEMM: hid = relu(x4 @ pe_w1^T + b1)  (4096x256, K=6144) ----------------
__global__ __launch_bounds__(256) void k_embed1(const float* __restrict__ A, const float* __restrict__ Wm,
                         const float* __restrict__ bias, float* __restrict__ Cc) {
  __shared__ float As[16][65];
  __shared__ float Bs[16][65];
  int bn = blockIdx.x, bm = blockIdx.y;
  int t = threadIdx.x, tx = t & 15, ty = t >> 4;
  int m0 = bm * 64, n0 = bn * 64;
  float acc[4][4] = {};
  for (int k0 = 0; k0 < 6144; k0 += 16) {
    int mr = t >> 2, kq = (t & 3) * 4;
    float4 a = *(const float4*)(A + (long long)(m0 + mr) * 6144 + k0 + kq);
    As[kq][mr] = a.x; As[kq + 1][mr] = a.y; As[kq + 2][mr] = a.z; As[kq + 3][mr] = a.w;
    float4 bv = *(const float4*)(Wm + (long long)(n0 + mr) * 6144 + k0 + kq);
    Bs[kq][mr] = bv.x; Bs[kq + 1][mr] = bv.y; Bs[kq + 2][mr] = bv.z; Bs[kq + 3][mr] = bv.w;
    __syncthreads();
#pragma unroll
    for (int kkk = 0; kkk < 16; ++kkk) {
      float av[4], bb[4];
#pragma unroll
      for (int i = 0; i < 4; ++i) av[i] = As[kkk][ty + 16 * i];
#pragma unroll
      for (int j = 0; j < 4; ++j) bb[j] = Bs[kkk][tx + 16 * j];
#pragma unroll
      for (int i = 0; i < 4; ++i)
#pragma unroll
        for (int j = 0; j < 4; ++j) acc[i][j] += av[i] * bb[j];
    }
    __syncthreads();
  }
#pragma unroll
  for (int i = 0; i < 4; ++i)
#pragma unroll
    for (int j = 0; j < 4; ++j) {
      int m = m0 + ty + 16 * i, n = n0 + tx + 16 * j;
      Cc[(long long)m * 256 + n] = fmaxf(acc[i][j] + bias[n], 0.f);
    }
}

// ---------------- embed stage 2 + l2 norm ----------------
__global__ __launch_bounds__(64) void k_embed2(const float* __restrict__ hid, const float* __restrict__ w2,
                        const float* __restrict__ b2, float* __restrict__ emb) {
  __shared__ float hrow[256];
  int pa = blockIdx.x, t = threadIdx.x;
  const float* hp = hid + (long long)pa * 256;
  for (int i = t; i < 256; i += 64) hrow[i] = hp[i];
  __syncthreads();
  float acc = 0.f;
  if (t < 30) {
    acc = b2[t];
    const float* wp = w2 + t * 256;
    for (int j = 0; j < 256; ++j) acc += wp[j] * hrow[j];
  }
  float sq = (t < 30) ? acc * acc : 0.f;
  for (int off = 32; off; off >>= 1) sq += __shfl_down(sq, off);
  float ss = __shfl(sq, 0);
  float scale = 1.f / (sqrtf(ss) + EPSG);
  if (t < 30) emb[(long long)pa * 30 + t] = acc * scale;
}

// ---------------- cur stats over emb per batch ----------------
__global__ void k_curstats(const float* __restrict__ emb, float* __restrict__ stats) {
  int b = blockIdx.x, t = threadIdx.x;
  const float* p = emb + (long long)b * 30720;
  float s = 0.f, ss = 0.f;
  for (int i = t; i < 30720; i += 256) { float x = p[i]; s += x; ss += x * x; }
  __shared__ float r1[256], r2[256];
  r1[t] = s; r2[t] = ss; __syncthreads();
  for (int st = 128; st; st >>= 1) {
    if (t < st) { r1[t] += r1[t + st]; r2[t] += r2[t + st]; }
    __syncthreads();
  }
  if (t == 0) {
    float n = 30720.f, m = r1[0] / n;
    stats[8 + b] = m;
    stats[12 + b] = sqrtf(fmaxf(r2[0] / n - m * m, 0.f) + EPSG);
  }
}

// ---------------- global-attention exp scores ----------------
__global__ void k_gatt(const float* __restrict__ emb, const float* __restrict__ alpha,
                       const float* __restrict__ beta, float* __restrict__ att) {
  __shared__ float er[64][33];
  __shared__ float ec[64][33];
  int b = blockIdx.x, r0 = blockIdx.y * 64, t = threadIdx.x;
  const float* eb = emb + (long long)b * 30720;
  for (int f = t; f < 1920; f += 256) er[f / 30][f % 30] = eb[(r0 + f / 30) * 30 + f % 30];
  float ca = ATT_Ac * alpha[0], cb = ATT_Bc * beta[0];
  int lane = t & 63, w = t >> 6;
  for (int c0 = 0; c0 < 1024; c0 += 64) {
    __syncthreads();
    for (int f = t; f < 1920; f += 256) ec[f / 30][f % 30] = eb[(c0 + f / 30) * 30 + f % 30];
    __syncthreads();
    for (int rr = w; rr < 64; rr += 4) {
      float acc = 0.f;
#pragma unroll
      for (int d = 0; d < 30; ++d) acc += er[rr][d] * ec[lane][d];
      att[((long long)b * 1024 + r0 + rr) * 1024 + c0 + lane] = __expf(ca * acc + cb);
    }
  }
}

// ---------------- row sums of att ----------------
__global__ void k_rowsum(const float* __restrict__ att, float* __restrict__ rowsum) {
  int row = blockIdx.x * 4 + (threadIdx.x >> 6);
  int lane = threadIdx.x & 63;
  const float4* p = (const float4*)(att + (long long)row * 1024);
  float s = 0.f;
  for (int i = lane; i < 256; i += 64) { float4 x = p[i]; s += x.x + x.y + x.z + x.w; }
  for (int off = 32; off; off >>= 1) s += __shfl_down(s, off);
  if (lane == 0) rowsum[row] = s;
}

// ---------------- rw GEMM (per batch 1024x6144, K=1024) + norm/AdaIN epilogue ----------------
__global__ __launch_bounds__(256) void k_rw(const float* __restrict__ att, const float* __restrict__ x4,
                     const float* __restrict__ rowsum, const float* __restrict__ stats,
                     float* __restrict__ rw) {
  __shared__ float As[8][130];
  __shared__ float Bs[8][132];
  int b = blockIdx.z;
  int n0 = blockIdx.x * 128, m0 = blockIdx.y * 128;
  const float* A = att + (long long)b * 1048576;
  const float* Bm = x4 + (long long)b * 6291456;
  int t = threadIdx.x, tx = t & 15, ty = t >> 4;
  float acc[8][8] = {};
  for (int k0 = 0; k0 < 1024; k0 += 8) {
    {
      int m = t >> 1, kq = (t & 1) * 4;
      float4 a = *(const float4*)(A + (long long)(m0 + m) * 1024 + k0 + kq);
      As[kq][m] = a.x; As[kq + 1][m] = a.y; As[kq + 2][m] = a.z; As[kq + 3][m] = a.w;
    }
    {
      int kq = t >> 5, n = (t & 31) * 4;
      float4 bv = *(const float4*)(Bm + (long long)(k0 + kq) * 6144 + n0 + n);
      *(float4*)&Bs[kq][n] = bv;
    }
    __syncthreads();
#pragma unroll
    for (int kkk = 0; kkk < 8; ++kkk) {
      float av[8], bb[8];
#pragma unroll
      for (int i = 0; i < 8; ++i) av[i] = As[kkk][ty + 16 * i];
#pragma unroll
      for (int j = 0; j < 8; ++j) bb[j] = Bs[kkk][tx + 16 * j];
#pragma unroll
      for (int i = 0; i < 8; ++i)
#pragma unroll
        for (int j = 0; j < 8; ++j) acc[i][j] += av[i] * bb[j];
    }
    __syncthreads();
  }
  float sm = stats[b], ssd = stats[4 + b], cm = stats[8 + b], cs = stats[12 + b];
  float inv_cs = 1.f / cs;
#pragma unroll
  for (int i = 0; i < 8; ++i) {
    int m = m0 + ty + 16 * i;
    float sc = 1.f / (rowsum[b * 1024 + m] + EPSG);
    float* dst = rw + ((long long)b * 1024 + m) * 6144 + n0;
#pragma unroll
    for (int j = 0; j < 8; ++j) {
      float val = acc[i][j] * sc;
      val = (val - cm) * inv_cs * ssd + sm;
      dst[tx + 16 * j] = val;
    }
  }
}

// ---------------- depthwise 5x5 conv, reflect pad ----------------
template <bool RELU>
__global__ void k_dwconv(const float* __restrict__ in, const float* __restrict__ w,
                         const float* __restrict__ bias, float* __restrict__ out) {
  int x = blockIdx.x * 64 + threadIdx.x;
  int y = blockIdx.y * 4 + threadIdx.y;
  int bc = blockIdx.z, c = bc % 96;
  const float* ip = in + (long long)bc * 65536;
  const float* wp = w + c * 25;
  float acc = bias[c];
#pragma unroll
  for (int ky = 0; ky < 5; ++ky) {
    int iy = y + ky - 2;
    iy = iy < 0 ? -iy : (iy > 255 ? 510 - iy : iy);
    const float* row = ip + iy * 256;
#pragma unroll
    for (int kx = 0; kx < 5; ++kx) {
      int ix = x + kx - 2;
      ix = ix < 0 ? -ix : (ix > 255 ? 510 - ix : ix);
      acc += wp[ky * 5 + kx] * row[ix];
    }
  }
  out[(long long)bc * 65536 + y * 256 + x] = RELU ? fmaxf(acc, 0.f) : acc;
}

// ---------------- window reverse + add hf -> feats_sum ----------------
__global__ void k_fs(const float* __restrict__ rw, const float* __restrict__ hf,
                     float* __restrict__ fs) {
  __shared__ float tile[64 * 97];
  int win = blockIdx.x;
  int b = win >> 10, wy = (win >> 5) & 31, wx = win & 31;
  int t = threadIdx.x;
  const float* src = rw + (long long)win * 6144;
  for (int f = t; f < 6144; f += 256) tile[(f / 96) * 97 + f % 96] = src[f];
  __syncthreads();
  long long obase = (long long)b * 96 * 65536;
  for (int f = t; f < 6144; f += 256) {
    int c = f >> 6, p = f & 63;
    long long oidx = obase + (long long)c * 65536 + (wy * 8 + (p >> 3)) * 256 + wx * 8 + (p & 7);
    fs[oidx] = tile[p * 97 + c] + hf[oidx];
  }
}

// ---------------- SKFusion conv1 3x3 s2 p1 + relu ----------------
__global__ void k_conv1(const float* __restrict__ fs, const float* __restrict__ w,
                        float* __restrict__ out) {
  int ox = blockIdx.x * 64 + threadIdx.x;
  int oy = blockIdx.y * 4 + threadIdx.y;
  int z = blockIdx.z, b = z / 6, og = z % 6, oc0 = og * 8;
  const float* ip = fs + (long long)b * 96 * 65536;
  float acc[8] = {};
  for (int ic = 0; ic < 96; ++ic) {
    const float* plane = ip + (long long)ic * 65536;
    float xv[3][3];
#pragma unroll
    for (int ky = 0; ky < 3; ++ky) {
      int iy = 2 * oy + ky - 1;
#pragma unroll
      for (int kx = 0; kx < 3; ++kx) {
        int ix = 2 * ox + kx - 1;
        xv[ky][kx] = (iy >= 0 && iy < 256 && ix >= 0 && ix < 256) ? plane[iy * 256 + ix] : 0.f;
      }
    }
#pragma unroll
    for (int o = 0; o < 8; ++o) {
      const float* wp = w + ((oc0 + o) * 96 + ic) * 9;
      acc[o] += wp[0] * xv[0][0] + wp[1] * xv[0][1] + wp[2] * xv[0][2]
              + wp[3] * xv[1][0] + wp[4] * xv[1][1] + wp[5] * xv[1][2]
              + wp[6] * xv[2][0] + wp[7] * xv[2][1] + wp[8] * xv[2][2];
    }
  }
#pragma unroll
  for (int o = 0; o < 8; ++o)
    out[(((long long)b * 48 + oc0 + o) * 128 + oy) * 128 + ox] = fmaxf(acc[o], 0.f);
}

// ---------------- SKFusion conv2 3x3 s2 p1 + partial pooling ----------------
__global__ void k_conv2pool(const float* __restrict__ c1, const float* __restrict__ w,
                            float* __restrict__ part) {
  int b = blockIdx.x, og = blockIdx.y, split = blockIdx.z, oc0 = og * 8;
  int t = threadIdx.x;
  const float* ip = c1 + (long long)b * 48 * 16384;
  float acc[8] = {};
  for (int pi = 0; pi < 2; ++pi) {
    int p = split * 512 + pi * 256 + t;
    int oy = p >> 6, ox = p & 63;
    for (int ic = 0; ic < 48; ++ic) {
      const float* plane = ip + ic * 16384;
      float xv[3][3];
#pragma unroll
      for (int ky = 0; ky < 3; ++ky) {
        int iy = 2 * oy + ky - 1;
#pragma unroll
        for (int kx = 0; kx < 3; ++kx) {
          int ix = 2 * ox + kx - 1;
          xv[ky][kx] = (iy >= 0 && iy < 128 && ix >= 0 && ix < 128) ? plane[iy * 128 + ix] : 0.f;
        }
      }
#pragma unroll
      for (int o = 0; o < 8; ++o) {
        const float* wp = w + ((oc0 + o) * 48 + ic) * 9;
        acc[o] += wp[0] * xv[0][0] + wp[1] * xv[0][1] + wp[2] * xv[0][2]
                + wp[3] * xv[1][0] + wp[4] * xv[1][1] + wp[5] * xv[1][2]
                + wp[6] * xv[2][0] + wp[7] * xv[2][1] + wp[8] * xv[2][2];
      }
    }
  }
  __shared__ float red[256];
  for (int o = 0; o < 8; ++o) {
    red[t] = acc[o]; __syncthreads();
    for (int st = 128; st; st >>= 1) {
      if (t < st) red[t] += red[t + st];
      __syncthreads();
    }
    if (t == 0) part[((b * 12 + og) * 8 + split) * 8 + o] = red[0];
    __syncthreads();
  }
}

// ---------------- gate: reduce partials + channel softmax ----------------
__global__ void k_gate(const float* __restrict__ part, float* __restrict__ gate) {
  int b = blockIdx.x, t = threadIdx.x;  // block 128
  __shared__ float val[96];
  __shared__ float red[128];
  if (t < 96) {
    int og = t / 8, o = t % 8;
    float s = 0.f;
    for (int sp = 0; sp < 8; ++sp) s += part[((b * 12 + og) * 8 + sp) * 8 + o];
    val[t] = s / 4096.f;
  }
  __syncthreads();
  float m = (t < 96) ? val[t] : -1e30f;
  red[t] = m; __syncthreads();
  for (int st = 64; st; st >>= 1) { if (t < st) red[t] = fmaxf(red[t], red[t + st]); __syncthreads(); }
  float mx = red[0]; __syncthreads();
  float e = (t < 96) ? __expf(val[t] - mx) : 0.f;
  red[t] = e; __syncthreads();
  for (int st = 64; st; st >>= 1) { if (t < st) red[t] += red[t + st]; __syncthreads(); }
  if (t < 96) gate[b * 96 + t] = e / red[0];
}

// ---------------- final: out = feats_sum * gate[b,c] ----------------
__global__ void k_final(const float* __restrict__ fs, const float* __restrict__ gate,
                        float* __restrict__ out) {
  long long i0 = ((long long)blockIdx.x * 256 + threadIdx.x) * 4;
  long long stride = (long long)gridDim.x * 1024;
  for (long long i = i0; i < 25165824LL; i += stride) {
    float4 x = *(const float4*)(fs + i);
    float g = gate[(int)(i >> 16)];   // i/65536 == b*96 + c
    x.x *= g; x.y *= g; x.z *= g; x.w *= g;
    *(float4*)(out + i) = x;
  }
}

// ---------------- launch ----------------
extern "C" void kernel_launch(void* const* d_in, const int* in_sizes, int n_in,
                              void* d_out, int out_size, void* d_ws, size_t ws_size,
                              hipStream_t stream) {
  const float* X      = (const float*)d_in[0];
  const float* hf_w1  = (const float*)d_in[1];
  const float* hf_b1  = (const float*)d_in[2];
  const float* hf_w2  = (const float*)d_in[3];
  const float* hf_b2  = (const float*)d_in[4];
  const float* lfv_w  = (const float*)d_in[5];
  const float* lfv_b  = (const float*)d_in[6];
  const float* lfqk_w = (const float*)d_in[7];
  const float* lfqk_b = (const float*)d_in[8];
  const float* mw1    = (const float*)d_in[9];
  const float* mb1    = (const float*)d_in[10];
  const float* mw2    = (const float*)d_in[11];
  const float* mb2    = (const float*)d_in[12];
  const float* pe_w1  = (const float*)d_in[13];
  const float* pe_b1  = (const float*)d_in[14];
  const float* pe_w2  = (const float*)d_in[15];
  const float* pe_b2  = (const float*)d_in[16];
  const float* aalpha = (const float*)d_in[17];
  const float* abeta  = (const float*)d_in[18];
  const float* fus_w1 = (const float*)d_in[19];
  const float* fus_w2 = (const float*)d_in[20];

  float* W = (float*)d_ws;
  float* q    = W;                 // BIG
  float* kbuf = W + BIG;           // BIG
  float* aw   = W + 2 * BIG;       // BIG  (x4)
  float* rw   = W + BIG;           // alias kbuf (free after attention)
  float* hf1  = W;                 // alias q    (free after attention)
  float* fs   = W + 2 * BIG;       // alias aw   (free after rw GEMM)
  float* SM   = W + 3 * BIG;
  float* bias_tab = SM;                  // 12288
  float* wt       = SM + 12288;          // 27648
  float* bqv      = SM + 39936;          // 288
  float* hid      = SM + 40224;          // 1048576
  float* emb      = SM + 1088800;        // 122880
  float* att      = SM + 1211680;        // 4194304
  float* rowsum   = SM + 5405984;        // 4096
  float* part_src = SM + 5410080;        // 1024
  float* stats    = SM + 5411104;        // 16
  float* part_pool= SM + 5411120;        // 3072
  float* gate     = SM + 5414192;        // 384
  float* c1       = SM + 5414576;        // 3145728
  float* v  = (float*)d_out;             // v buffer aliases d_out
  float* hf = (float*)d_out;             // then hf aliases d_out

  k_wt<<<108, 256, 0, stream>>>(lfqk_w, lfqk_b, lfv_w, lfv_b, wt, bqv);
  k_bias<<<16, 256, 0, stream>>>(mw1, mb1, mw2, mb2, bias_tab);
  k_qkv<<<NWINS, 256, 0, stream>>>(X, wt, bqv, q, kbuf, v);
  k_attn<<<NWINS, 192, 0, stream>>>(q, kbuf, v, bias_tab, aw);
  k_redA<<<dim3(4, 128), 256, 0, stream>>>(aw, part_src);
  k_redB<<<4, 128, 0, stream>>>(part_src, stats);
  k_embed1<<<dim3(4, 64), 256, 0, stream>>>(aw, pe_w1, pe_b1, hid);
  k_embed2<<<4096, 64, 0, stream>>>(hid, pe_w2, pe_b2, emb);
  k_curstats<<<4, 256, 0, stream>>>(emb, stats);
  k_gatt<<<dim3(4, 16), 256, 0, stream>>>(emb, aalpha, abeta, att);
  k_rowsum<<<1024, 256, 0, stream>>>(att, rowsum);
  k_rw<<<dim3(48, 8, 4), 256, 0, stream>>>(att, aw, rowsum, stats, rw);
  k_dwconv<true><<<dim3(4, 64, 384), dim3(64, 4), 0, stream>>>(X, hf_w1, hf_b1, hf1);
  k_dwconv<false><<<dim3(4, 64, 384), dim3(64, 4), 0, stream>>>(hf1, hf_w2, hf_b2, hf);
  k_fs<<<NWINS, 256, 0, stream>>>(rw, hf, fs);
  k_conv1<<<dim3(2, 32, 24), dim3(64, 4), 0, stream>>>(fs, fus_w1, c1);
  k_conv2pool<<<dim3(4, 12, 8), 256, 0, stream>>>(c1, fus_w2, part_pool);
  k_gate<<<4, 128, 0, stream>>>(part_pool, gate);
  k_final<<<2048, 256, 0, stream>>>(fs, gate, (float*)d_out);
}

// Round 2
// 1899.854 us; speedup vs baseline: 1.4339x; 1.4339x over previous
//
#include <hip/hip_runtime.h>

// ---------------- constants ----------------
constexpr int B_ = 4, C_ = 96, H_ = 256, W_ = 256;
constexpr int NWINS = 4096;              // B*nh*nw
constexpr float EPSG = 1e-8f;
constexpr float ATT_Ac = 30.f, ATT_Bc = 20.f;
constexpr float QSCALE = 0.17677669529663687f;  // 32^-0.5
constexpr long long BIG = (long long)B_ * C_ * H_ * W_;  // 25165824

typedef unsigned short u16;
typedef unsigned int u32;
typedef __attribute__((ext_vector_type(8))) __bf16 bf16x8;
typedef __attribute__((ext_vector_type(4))) float f32x4;

#define AS(n) __attribute__((address_space(n)))

__device__ __forceinline__ void gload16(const void* g, void* l) {
  __builtin_amdgcn_global_load_lds((AS(1) void*)g, (AS(3) void*)l, 16, 0, 0);
}

__device__ __forceinline__ u16 f2b(float f) {
  union { float f; u32 i; } x; x.f = f;
  u32 r = (x.i + 0x7fffu + ((x.i >> 16) & 1u)) >> 16;
  return (u16)r;
}
__device__ __forceinline__ float blo(u32 u) { union { u32 i; float f; } x; x.i = u << 16; return x.f; }
__device__ __forceinline__ float bhi(u32 u) { union { u32 i; float f; } x; x.i = u & 0xffff0000u; return x.f; }

// ---------------- weight transpose for qkv ----------------
__global__ void k_wt(const float* __restrict__ lfqk_w, const float* __restrict__ lfqk_b,
                     const float* __restrict__ lfv_w, const float* __restrict__ lfv_b,
                     float* __restrict__ wt, float* __restrict__ bq) {
  int t = blockIdx.x * 256 + threadIdx.x;
  if (t < 96 * 288) {
    int ic = t / 288, oc = t % 288;
    wt[t] = (oc < 192) ? lfqk_w[oc * 96 + ic] : lfv_w[(oc - 192) * 96 + ic];
  }
  if (t < 288) bq[t] = (t < 192) ? lfqk_b[t] : lfv_b[t - 192];
}

// ---------------- relative-position bias MLP ----------------
__global__ void k_bias(const float* __restrict__ w1, const float* __restrict__ b1,
                       const float* __restrict__ w2, const float* __restrict__ b2,
                       float* __restrict__ bias) {
  int t = blockIdx.x * 256 + threadIdx.x;
  if (t >= 4096) return;
  int n = t >> 6, m = t & 63;
  float dy = (float)((n >> 3) - (m >> 3));
  float dx = (float)((n & 7) - (m & 7));
  float fy = (dy > 0.f ? 1.f : (dy < 0.f ? -1.f : 0.f)) * log1pf(fabsf(dy));
  float fx = (dx > 0.f ? 1.f : (dx < 0.f ? -1.f : 0.f)) * log1pf(fabsf(dx));
  float o0 = b2[0], o1 = b2[1], o2 = b2[2];
  for (int j = 0; j < 256; ++j) {
    float h = fmaxf(w1[2 * j] * fy + w1[2 * j + 1] * fx + b1[j], 0.f);
    o0 += w2[j] * h; o1 += w2[256 + j] * h; o2 += w2[512 + j] * h;
  }
  bias[t] = o0; bias[4096 + t] = o1; bias[8192 + t] = o2;
}

// ---------------- fp32 -> bf16 convert (pe_w1) ----------------
__global__ void k_cvtw(const float* __restrict__ in, u16* __restrict__ out, int n) {
  int i = (blockIdx.x * 256 + threadIdx.x) * 4;
  if (i < n) {
    float4 v = *(const float4*)(in + i);
    out[i] = f2b(v.x); out[i + 1] = f2b(v.y); out[i + 2] = f2b(v.z); out[i + 3] = f2b(v.w);
  }
}

// ---------------- qkv 1x1 conv into window layout ----------------
__global__ __launch_bounds__(256) void k_qkv(const float* __restrict__ X,
                      const float* __restrict__ wt, const float* __restrict__ bq,
                      float* __restrict__ q, float* __restrict__ k, float* __restrict__ v) {
  __shared__ float xw[96][64];
  int win = blockIdx.x;
  int b = win >> 10, wy = (win >> 5) & 31, wx = win & 31;
  int t = threadIdx.x;
  const float* Xb = X + (long long)b * 96 * 65536 + wy * 8 * 256 + wx * 8;
  for (int f = t; f < 6144; f += 256) {
    int ic = f >> 6, p = f & 63;
    xw[ic][p] = Xb[ic * 65536 + (p >> 3) * 256 + (p & 7)];
  }
  __syncthreads();
  int lane = t & 63, quad = t >> 6;
  int nbase = quad * 16;
  for (int ob = 0; ob < 288; ob += 64) {
    int oc = ob + lane;
    if (oc < 288) {
      float acc[16];
#pragma unroll
      for (int i = 0; i < 16; ++i) acc[i] = 0.f;
#pragma unroll 4
      for (int ic = 0; ic < 96; ++ic) {
        float wv = wt[ic * 288 + oc];
        const float4* xr = (const float4*)&xw[ic][nbase];
#pragma unroll
        for (int g = 0; g < 4; ++g) {
          float4 x = xr[g];
          acc[4 * g + 0] += wv * x.x; acc[4 * g + 1] += wv * x.y;
          acc[4 * g + 2] += wv * x.z; acc[4 * g + 3] += wv * x.w;
        }
      }
      float bb = bq[oc];
      int s = oc / 96, c = oc % 96;
      float scale = (s == 0) ? QSCALE : 1.f;
      float* dst = ((s == 0) ? q : (s == 1) ? k : v) + (long long)win * 6144 + c;
#pragma unroll
      for (int i = 0; i < 16; ++i) dst[(nbase + i) * 96] = (acc[i] + bb) * scale;
    }
  }
}

// ---------------- window attention -> awB (bf16) ----------------
__global__ __launch_bounds__(192) void k_attn(const float* __restrict__ q, const float* __restrict__ kk_,
                       const float* __restrict__ v, const float* __restrict__ bias,
                       u16* __restrict__ awB) {
  __shared__ float kl[3][64][32];
  __shared__ float vl[3][64][32];
  int win = blockIdx.x;
  int t = threadIdx.x;
  long long base = (long long)win * 6144;
  for (int f = t; f < 6144; f += 192) {
    int n = f / 96, c = f % 96, h = c >> 5, d = c & 31;
    kl[h][n][d] = kk_[base + f];
    vl[h][n][d] = v[base + f];
  }
  __syncthreads();
  int h = t >> 6, lane = t & 63;
  float qr[32];
  const float4* qp = (const float4*)(q + base + lane * 96 + h * 32);
#pragma unroll
  for (int i = 0; i < 8; ++i) {
    float4 x = qp[i];
    qr[4 * i] = x.x; qr[4 * i + 1] = x.y; qr[4 * i + 2] = x.z; qr[4 * i + 3] = x.w;
  }
  const float* bh = bias + h * 4096 + lane * 64;
  float s[64];
#pragma unroll
  for (int m = 0; m < 64; ++m) {
    float acc = 0.f;
    const float4* kp = (const float4*)kl[h][m];
#pragma unroll
    for (int i = 0; i < 8; ++i) {
      float4 x = kp[i];
      acc += qr[4 * i] * x.x + qr[4 * i + 1] * x.y + qr[4 * i + 2] * x.z + qr[4 * i + 3] * x.w;
    }
    s[m] = acc + bh[m];
  }
  float mx = -1e30f;
#pragma unroll
  for (int m = 0; m < 64; ++m) mx = fmaxf(mx, s[m]);
  float sum = 0.f;
#pragma unroll
  for (int m = 0; m < 64; ++m) { float p = __expf(s[m] - mx); s[m] = p; sum += p; }
  float inv = 1.f / sum;
  float o[32];
#pragma unroll
  for (int d = 0; d < 32; ++d) o[d] = 0.f;
#pragma unroll
  for (int m = 0; m < 64; ++m) {
    float p = s[m];
    const float4* vp = (const float4*)vl[h][m];
#pragma unroll
    for (int i = 0; i < 8; ++i) {
      float4 x = vp[i];
      o[4 * i] += p * x.x; o[4 * i + 1] += p * x.y; o[4 * i + 2] += p * x.z; o[4 * i + 3] += p * x.w;
    }
  }
  u32 pk[16];
#pragma unroll
  for (int j = 0; j < 16; ++j)
    pk[j] = (u32)f2b(o[2 * j] * inv) | ((u32)f2b(o[2 * j + 1] * inv) << 16);
  u32* op = (u32*)(awB + base + lane * 96 + h * 32);
#pragma unroll
  for (int j = 0; j < 16; ++j) op[j] = pk[j];
}

// ---------------- transpose awB [b][p][f] -> awT [b][f][p] (bf16) ----------------
__global__ __launch_bounds__(256) void k_awT(const u16* __restrict__ awB, u16* __restrict__ awT) {
  __shared__ u16 tile[64][80];
  int f0 = blockIdx.x * 64, p0 = blockIdx.y * 64, b = blockIdx.z;
  int t = threadIdx.x;
  const u16* src = awB + ((long long)b * 1024 + p0) * 6144 + f0;
  int pr = t >> 2, fc = (t & 3) * 16;
  uint4 v0 = *(const uint4*)(src + (long long)pr * 6144 + fc);
  uint4 v1 = *(const uint4*)(src + (long long)pr * 6144 + fc + 8);
  u16 e[16];
  *(uint4*)&e[0] = v0; *(uint4*)&e[8] = v1;
#pragma unroll
  for (int j = 0; j < 16; ++j) tile[fc + j][pr] = e[j];
  __syncthreads();
  int fr = t >> 2, pc = (t & 3) * 16;
  u16* dst = awT + ((long long)b * 6144 + f0 + fr) * 1024 + p0 + pc;
  *(uint4*)(dst) = *(const uint4*)&tile[fr][pc];
  *(uint4*)(dst + 8) = *(const uint4*)&tile[fr][pc + 8];
}

// ---------------- src stats from awB (bf16) ----------------
__global__ void k_redA(const u16* __restrict__ awB, float* __restrict__ part) {
  int b = blockIdx.x, blk = blockIdx.y, t = threadIdx.x;
  const uint4* p = (const uint4*)(awB + (long long)b * 6291456 + (long long)blk * 49152);
  float s = 0.f, ss = 0.f;
  for (int i = t; i < 6144; i += 256) {
    uint4 x = p[i];
    u32 w[4] = {x.x, x.y, x.z, x.w};
#pragma unroll
    for (int j = 0; j < 4; ++j) {
      float a = blo(w[j]), c = bhi(w[j]);
      s += a + c; ss += a * a + c * c;
    }
  }
  __shared__ float r1[256], r2[256];
  r1[t] = s; r2[t] = ss; __syncthreads();
  for (int st = 128; st; st >>= 1) {
    if (t < st) { r1[t] += r1[t + st]; r2[t] += r2[t + st]; }
    __syncthreads();
  }
  if (t == 0) { part[(b * 128 + blk) * 2] = r1[0]; part[(b * 128 + blk) * 2 + 1] = r2[0]; }
}

__global__ void k_redB(const float* __restrict__ part, float* __restrict__ stats) {
  int b = blockIdx.x, t = threadIdx.x;
  float s = part[(b * 128 + t) * 2], ss = part[(b * 128 + t) * 2 + 1];
  __shared__ float r1[128], r2[128];
  r1[t] = s; r2[t] = ss; __syncthreads();
  for (int st = 64; st; st >>= 1) {
    if (t < st) { r1[t] += r1[t + st]; r2[t] += r2[t + st]; }
    __syncthreads();
  }
  if (t == 0) {
    float n = 6291456.f, m = r1[0] / n;
    stats[b] = m;
    stats[4 + b] = sqrtf(fmaxf(r2[0] / n - m * m, 0.f) + EPSG);
  }
}

// ---------------- patch-embed GEMM (MFMA): hid = relu(awB @ peB^T + b1) ----------------
// M=4096, N=256, K=6144; BM=128, BN=64, BK=32
__global__ __launch_bounds__(256) void k_embed1(const u16* __restrict__ awB, const u16* __restrict__ peB,
                         const float* __restrict__ b1, float* __restrict__ hid) {
  __shared__ __align__(16) u16 As[128 * 32];
  __shared__ __align__(16) u16 Bs[64 * 32];
  int n0 = blockIdx.x * 64, m0 = blockIdx.y * 128;
  int t = threadIdx.x;
  const u16* Ag = awB + (long long)m0 * 6144;
  const u16* Bg = peB + (long long)n0 * 6144;
  f32x4 acc[4][2];
  f32x4 z = {0.f, 0.f, 0.f, 0.f};
#pragma unroll
  for (int i = 0; i < 4; ++i) { acc[i][0] = z; acc[i][1] = z; }
  int w = t >> 6, l = t & 63;
  int wm = (w >> 1) * 64, wn = (w & 1) * 32;
  int ro = l & 15, ko = (l >> 4) * 16;
  for (int k0 = 0; k0 < 6144; k0 += 32) {
#pragma unroll
    for (int i = 0; i < 2; ++i) {
      int c = t + 256 * i;
      gload16(Ag + (long long)(c >> 2) * 6144 + k0 + (c & 3) * 8, (char*)As + c * 16);
    }
    gload16(Bg + (long long)(t >> 2) * 6144 + k0 + (t & 3) * 8, (char*)Bs + t * 16);
    __syncthreads();
    bf16x8 a[4], bb[2];
#pragma unroll
    for (int fm = 0; fm < 4; ++fm)
      a[fm] = *(const bf16x8*)((const char*)As + (wm + fm * 16 + ro) * 64 + ko);
#pragma unroll
    for (int fn = 0; fn < 2; ++fn)
      bb[fn] = *(const bf16x8*)((const char*)Bs + (wn + fn * 16 + ro) * 64 + ko);
#pragma unroll
    for (int fm = 0; fm < 4; ++fm)
#pragma unroll
      for (int fn = 0; fn < 2; ++fn)
        acc[fm][fn] = __builtin_amdgcn_mfma_f32_16x16x32_bf16(a[fm], bb[fn], acc[fm][fn], 0, 0, 0);
    __syncthreads();
  }
#pragma unroll
  for (int fm = 0; fm < 4; ++fm)
#pragma unroll
    for (int r = 0; r < 4; ++r) {
      int m = m0 + wm + fm * 16 + (l >> 4) * 4 + r;
#pragma unroll
      for (int fn = 0; fn < 2; ++fn) {
        int n = n0 + wn + fn * 16 + (l & 15);
        hid[(long long)m * 256 + n] = fmaxf(acc[fm][fn][r] + b1[n], 0.f);
      }
    }
}

// ---------------- embed stage 2 + l2 norm ----------------
__global__ __launch_bounds__(64) void k_embed2(const float* __restrict__ hid, const float* __restrict__ w2,
                        const float* __restrict__ b2, float* __restrict__ emb) {
  __shared__ float hrow[256];
  int pa = blockIdx.x, t = threadIdx.x;
  const float* hp = hid + (long long)pa * 256;
  for (int i = t; i < 256; i += 64) hrow[i] = hp[i];
  __syncthreads();
  float acc = 0.f;
  if (t < 30) {
    acc = b2[t];
    const float* wp = w2 + t * 256;
    for (int j = 0; j < 256; ++j) acc += wp[j] * hrow[j];
  }
  float sq = (t < 30) ? acc * acc : 0.f;
  for (int off = 32; off; off >>= 1) sq += __shfl_down(sq, off);
  float ss = __shfl(sq, 0);
  float scale = 1.f / (sqrtf(ss) + EPSG);
  if (t < 30) emb[(long long)pa * 30 + t] = acc * scale;
}

// ---------------- cur stats over emb per batch ----------------
__global__ void k_curstats(const float* __restrict__ emb, float* __restrict__ stats) {
  int b = blockIdx.x, t = threadIdx.x;
  const float* p = emb + (long long)b * 30720;
  float s = 0.f, ss = 0.f;
  for (int i = t; i < 30720; i += 256) { float x = p[i]; s += x; ss += x * x; }
  __shared__ float r1[256], r2[256];
  r1[t] = s; r2[t] = ss; __syncthreads();
  for (int st = 128; st; st >>= 1) {
    if (t < st) { r1[t] += r1[t + st]; r2[t] += r2[t + st]; }
    __syncthreads();
  }
  if (t == 0) {
    float n = 30720.f, m = r1[0] / n;
    stats[8 + b] = m;
    stats[12 + b] = sqrtf(fmaxf(r2[0] / n - m * m, 0.f) + EPSG);
  }
}

// ---------------- global-attention exp scores -> bf16 ----------------
__global__ void k_gatt(const float* __restrict__ emb, const float* __restrict__ alpha,
                       const float* __restrict__ beta, u16* __restrict__ attB) {
  __shared__ float er[64][33];
  __shared__ float ec[64][33];
  int b = blockIdx.x, r0 = blockIdx.y * 64, t = threadIdx.x;
  const float* eb = emb + (long long)b * 30720;
  for (int f = t; f < 1920; f += 256) er[f / 30][f % 30] = eb[(r0 + f / 30) * 30 + f % 30];
  float ca = ATT_Ac * alpha[0], cb = ATT_Bc * beta[0];
  int lane = t & 63, w = t >> 6;
  for (int c0 = 0; c0 < 1024; c0 += 64) {
    __syncthreads();
    for (int f = t; f < 1920; f += 256) ec[f / 30][f % 30] = eb[(c0 + f / 30) * 30 + f % 30];
    __syncthreads();
    for (int rr = w; rr < 64; rr += 4) {
      float acc = 0.f;
#pragma unroll
      for (int d = 0; d < 30; ++d) acc += er[rr][d] * ec[lane][d];
      attB[((long long)b * 1024 + r0 + rr) * 1024 + c0 + lane] = f2b(__expf(ca * acc + cb));
    }
  }
}

// ---------------- row sums of attB ----------------
__global__ void k_rowsum(const u16* __restrict__ attB, float* __restrict__ rowsum) {
  int row = blockIdx.x * 4 + (threadIdx.x >> 6);
  int lane = threadIdx.x & 63;
  const uint4* p = (const uint4*)(attB + (long long)row * 1024);
  float s = 0.f;
  for (int i = lane; i < 128; i += 64) {
    uint4 x = p[i];
    s += blo(x.x) + bhi(x.x) + blo(x.y) + bhi(x.y) + blo(x.z) + bhi(x.z) + blo(x.w) + bhi(x.w);
  }
  for (int off = 32; off; off >>= 1) s += __shfl_down(s, off);
  if (lane == 0) rowsum[row] = s;
}

// ---------------- rw GEMM (MFMA, B^T form) + AdaIN epilogue ----------------
// per batch: M=1024, N=6144, K=1024; BM=BN=128, BK=32
__global__ __launch_bounds__(256) void k_rw(const u16* __restrict__ attB, const u16* __restrict__ x4T,
                     const float* __restrict__ rowsum, const float* __restrict__ stats,
                     float* __restrict__ rw) {
  __shared__ __align__(16) u16 As[128 * 32];
  __shared__ __align__(16) u16 Bs[128 * 32];
  int b = blockIdx.z;
  int n0 = blockIdx.x * 128, m0 = blockIdx.y * 128;
  const u16* Ag = attB + ((long long)b * 1024 + m0) * 1024;
  const u16* Bg = x4T + ((long long)b * 6144 + n0) * 1024;
  int t = threadIdx.x;
  f32x4 acc[4][4];
  f32x4 z = {0.f, 0.f, 0.f, 0.f};
#pragma unroll
  for (int i = 0; i < 4; ++i)
#pragma unroll
    for (int j = 0; j < 4; ++j) acc[i][j] = z;
  int w = t >> 6, l = t & 63;
  int wm = (w >> 1) * 64, wn = (w & 1) * 64;
  int ro = l & 15, ko = (l >> 4) * 16;
  for (int k0 = 0; k0 < 1024; k0 += 32) {
#pragma unroll
    for (int i = 0; i < 2; ++i) {
      int c = t + 256 * i;
      gload16(Ag + (c >> 2) * 1024 + k0 + (c & 3) * 8, (char*)As + c * 16);
      gload16(Bg + (c >> 2) * 1024 + k0 + (c & 3) * 8, (char*)Bs + c * 16);
    }
    __syncthreads();
    bf16x8 a[4], bb[4];
#pragma unroll
    for (int fm = 0; fm < 4; ++fm)
      a[fm] = *(const bf16x8*)((const char*)As + (wm + fm * 16 + ro) * 64 + ko);
#pragma unroll
    for (int fn = 0; fn < 4; ++fn)
      bb[fn] = *(const bf16x8*)((const char*)Bs + (wn + fn * 16 + ro) * 64 + ko);
#pragma unroll
    for (int fm = 0; fm < 4; ++fm)
#pragma unroll
      for (int fn = 0; fn < 4; ++fn)
        acc[fm][fn] = __builtin_amdgcn_mfma_f32_16x16x32_bf16(a[fm], bb[fn], acc[fm][fn], 0, 0, 0);
    __syncthreads();
  }
  float sm = stats[b], ssd = stats[4 + b], cm = stats[8 + b], inv_cs = 1.f / stats[12 + b];
#pragma unroll
  for (int fm = 0; fm < 4; ++fm)
#pragma unroll
    for (int r = 0; r < 4; ++r) {
      int m = m0 + wm + fm * 16 + (l >> 4) * 4 + r;
      float sc = 1.f / (rowsum[b * 1024 + m] + EPSG);
      float* dst = rw + ((long long)b * 1024 + m) * 6144 + n0 + wn + (l & 15);
#pragma unroll
      for (int fn = 0; fn < 4; ++fn) {
        float val = acc[fm][fn][r] * sc;
        dst[fn * 16] = (val - cm) * inv_cs * ssd + sm;
      }
    }
}

// ---------------- depthwise 5x5 conv, reflect pad ----------------
template <bool RELU>
__global__ void k_dwconv(const float* __restrict__ in, const float* __restrict__ w,
                         const float* __restrict__ bias, float* __restrict__ out) {
  int x = blockIdx.x * 64 + threadIdx.x;
  int y = blockIdx.y * 4 + threadIdx.y;
  int bc = blockIdx.z, c = bc % 96;
  const float* ip = in + (long long)bc * 65536;
  const float* wp = w + c * 25;
  float acc = bias[c];
#pragma unroll
  for (int ky = 0; ky < 5; ++ky) {
    int iy = y + ky - 2;
    iy = iy < 0 ? -iy : (iy > 255 ? 510 - iy : iy);
    const float* row = ip + iy * 256;
#pragma unroll
    for (int kx = 0; kx < 5; ++kx) {
      int ix = x + kx - 2;
      ix = ix < 0 ? -ix : (ix > 255 ? 510 - ix : ix);
      acc += wp[ky * 5 + kx] * row[ix];
    }
  }
  out[(long long)bc * 65536 + y * 256 + x] = RELU ? fmaxf(acc, 0.f) : acc;
}

// ---------------- window reverse + add hf -> feats_sum ----------------
__global__ void k_fs(const float* __restrict__ rw, const float* __restrict__ hf,
                     float* __restrict__ fs) {
  __shared__ float tile[64 * 97];
  int win = blockIdx.x;
  int b = win >> 10, wy = (win >> 5) & 31, wx = win & 31;
  int t = threadIdx.x;
  const float* src = rw + (long long)win * 6144;
  for (int f = t; f < 6144; f += 256) tile[(f / 96) * 97 + f % 96] = src[f];
  __syncthreads();
  long long obase = (long long)b * 96 * 65536;
  for (int f = t; f < 6144; f += 256) {
    int c = f >> 6, p = f & 63;
    long long oidx = obase + (long long)c * 65536 + (wy * 8 + (p >> 3)) * 256 + wx * 8 + (p & 7);
    fs[oidx] = tile[p * 97 + c] + hf[oidx];
  }
}

// ---------------- SKFusion conv1 3x3 s2 p1 + relu ----------------
__global__ void k_conv1(const float* __restrict__ fs, const float* __restrict__ w,
                        float* __restrict__ out) {
  int ox = blockIdx.x * 64 + threadIdx.x;
  int oy = blockIdx.y * 4 + threadIdx.y;
  int z = blockIdx.z, b = z / 6, og = z % 6, oc0 = og * 8;
  const float* ip = fs + (long long)b * 96 * 65536;
  float acc[8] = {};
  for (int ic = 0; ic < 96; ++ic) {
    const float* plane = ip + (long long)ic * 65536;
    float xv[3][3];
#pragma unroll
    for (int ky = 0; ky < 3; ++ky) {
      int iy = 2 * oy + ky - 1;
#pragma unroll
      for (int kx = 0; kx < 3; ++kx) {
        int ix = 2 * ox + kx - 1;
        xv[ky][kx] = (iy >= 0 && iy < 256 && ix >= 0 && ix < 256) ? plane[iy * 256 + ix] : 0.f;
      }
    }
#pragma unroll
    for (int o = 0; o < 8; ++o) {
      const float* wp = w + ((oc0 + o) * 96 + ic) * 9;
      acc[o] += wp[0] * xv[0][0] + wp[1] * xv[0][1] + wp[2] * xv[0][2]
              + wp[3] * xv[1][0] + wp[4] * xv[1][1] + wp[5] * xv[1][2]
              + wp[6] * xv[2][0] + wp[7] * xv[2][1] + wp[8] * xv[2][2];
    }
  }
#pragma unroll
  for (int o = 0; o < 8; ++o)
    out[(((long long)b * 48 + oc0 + o) * 128 + oy) * 128 + ox] = fmaxf(acc[o], 0.f);
}

// ---------------- SKFusion conv2 3x3 s2 p1 + partial pooling ----------------
__global__ void k_conv2pool(const float* __restrict__ c1, const float* __restrict__ w,
                            float* __restrict__ part) {
  int b = blockIdx.x, og = blockIdx.y, split = blockIdx.z, oc0 = og * 8;
  int t = threadIdx.x;
  const float* ip = c1 + (long long)b * 48 * 16384;
  float acc[8] = {};
  for (int pi = 0; pi < 2; ++pi) {
    int p = split * 512 + pi * 256 + t;
    int oy = p >> 6, ox = p & 63;
    for (int ic = 0; ic < 48; ++ic) {
      const float* plane = ip + ic * 16384;
      float xv[3][3];
#pragma unroll
      for (int ky = 0; ky < 3; ++ky) {
        int iy = 2 * oy + ky - 1;
#pragma unroll
        for (int kx = 0; kx < 3; ++kx) {
          int ix = 2 * ox + kx - 1;
          xv[ky][kx] = (iy >= 0 && iy < 128 && ix >= 0 && ix < 128) ? plane[iy * 128 + ix] : 0.f;
        }
      }
#pragma unroll
      for (int o = 0; o < 8; ++o) {
        const float* wp = w + ((oc0 + o) * 48 + ic) * 9;
        acc[o] += wp[0] * xv[0][0] + wp[1] * xv[0][1] + wp[2] * xv[0][2]
                + wp[3] * xv[1][0] + wp[4] * xv[1][1] + wp[5] * xv[1][2]
                + wp[6] * xv[2][0] + wp[7] * xv[2][1] + wp[8] * xv[2][2];
      }
    }
  }
  __shared__ float red[256];
  for (int o = 0; o < 8; ++o) {
    red[t] = acc[o]; __syncthreads();
    for (int st = 128; st; st >>= 1) {
      if (t < st) red[t] += red[t + st];
      __syncthreads();
    }
    if (t == 0) part[((b * 12 + og) * 8 + split) * 8 + o] = red[0];
    __syncthreads();
  }
}

// ---------------- gate: reduce partials + channel softmax ----------------
__global__ void k_gate(const float* __restrict__ part, float* __restrict__ gate) {
  int b = blockIdx.x, t = threadIdx.x;
  __shared__ float val[96];
  __shared__ float red[128];
  if (t < 96) {
    int og = t / 8, o = t % 8;
    float s = 0.f;
    for (int sp = 0; sp < 8; ++sp) s += part[((b * 12 + og) * 8 + sp) * 8 + o];
    val[t] = s / 4096.f;
  }
  __syncthreads();
  float m = (t < 96) ? val[t] : -1e30f;
  red[t] = m; __syncthreads();
  for (int st = 64; st; st >>= 1) { if (t < st) red[t] = fmaxf(red[t], red[t + st]); __syncthreads(); }
  float mx = red[0]; __syncthreads();
  float e = (t < 96) ? __expf(val[t] - mx) : 0.f;
  red[t] = e; __syncthreads();
  for (int st = 64; st; st >>= 1) { if (t < st) red[t] += red[t + st]; __syncthreads(); }
  if (t < 96) gate[b * 96 + t] = e / red[0];
}

// ---------------- final: out = feats_sum * gate[b,c] ----------------
__global__ void k_final(const float* __restrict__ fs, const float* __restrict__ gate,
                        float* __restrict__ out) {
  long long i0 = ((long long)blockIdx.x * 256 + threadIdx.x) * 4;
  long long stride = (long long)gridDim.x * 1024;
  for (long long i = i0; i < 25165824LL; i += stride) {
    float4 x = *(const float4*)(fs + i);
    float g = gate[(int)(i >> 16)];
    x.x *= g; x.y *= g; x.z *= g; x.w *= g;
    *(float4*)(out + i) = x;
  }
}

// ---------------- launch ----------------
extern "C" void kernel_launch(void* const* d_in, const int* in_sizes, int n_in,
                              void* d_out, int out_size, void* d_ws, size_t ws_size,
                              hipStream_t stream) {
  const float* X      = (const float*)d_in[0];
  const float* hf_w1  = (const float*)d_in[1];
  const float* hf_b1  = (const float*)d_in[2];
  const float* hf_w2  = (const float*)d_in[3];
  const float* hf_b2  = (const float*)d_in[4];
  const float* lfv_w  = (const float*)d_in[5];
  const float* lfv_b  = (const float*)d_in[6];
  const float* lfqk_w = (const float*)d_in[7];
  const float* lfqk_b = (const float*)d_in[8];
  const float* mw1    = (const float*)d_in[9];
  const float* mb1    = (const float*)d_in[10];
  const float* mw2    = (const float*)d_in[11];
  const float* mb2    = (const float*)d_in[12];
  const float* pe_w1  = (const float*)d_in[13];
  const float* pe_b1  = (const float*)d_in[14];
  const float* pe_w2  = (const float*)d_in[15];
  const float* pe_b2  = (const float*)d_in[16];
  const float* aalpha = (const float*)d_in[17];
  const float* abeta  = (const float*)d_in[18];
  const float* fus_w1 = (const float*)d_in[19];
  const float* fus_w2 = (const float*)d_in[20];

  float* W = (float*)d_ws;
  float* q    = W;                       // BIG fp32
  float* kbuf = W + BIG;                 // BIG fp32
  u16* awB = (u16*)(W + 2 * BIG);        // BIG bf16  (= BIG/2 floats)
  u16* awT = awB + BIG;                  // BIG bf16
  float* rw  = W;                        // alias q (dead after attn)
  float* hf1 = W + BIG;                  // alias kbuf (dead after attn)
  float* fs  = W + 2 * BIG;              // alias awB/awT (dead after rw GEMM)
  float* SM = W + 3 * BIG;
  float* bias_tab  = SM;                 // 12288
  float* wt        = SM + 12288;         // 27648
  float* bqv       = SM + 39936;         // 288
  float* hid       = SM + 40224;         // 1048576
  float* emb       = SM + 1088800;       // 122880
  u16*   attB      = (u16*)(SM + 1211680);   // 4194304 u16 = 2097152 f
  float* rowsum    = SM + 3308832;       // 4096
  float* part_src  = SM + 3312928;       // 1024
  float* stats     = SM + 3313952;       // 16
  float* part_pool = SM + 3313968;       // 3072
  float* gate      = SM + 3317040;       // 384
  float* c1        = SM + 3317424;       // 3145728
  u16*   peB       = (u16*)(SM + 6463152);   // 1572864 u16
  float* v  = (float*)d_out;             // v aliases d_out
  float* hf = (float*)d_out;             // then hf aliases d_out

  k_wt<<<108, 256, 0, stream>>>(lfqk_w, lfqk_b, lfv_w, lfv_b, wt, bqv);
  k_bias<<<16, 256, 0, stream>>>(mw1, mb1, mw2, mb2, bias_tab);
  k_cvtw<<<1536, 256, 0, stream>>>(pe_w1, peB, 256 * 6144);
  k_qkv<<<NWINS, 256, 0, stream>>>(X, wt, bqv, q, kbuf, v);
  k_attn<<<NWINS, 192, 0, stream>>>(q, kbuf, v, bias_tab, awB);
  k_awT<<<dim3(96, 16, 4), 256, 0, stream>>>(awB, awT);
  k_redA<<<dim3(4, 128), 256, 0, stream>>>(awB, part_src);
  k_redB<<<4, 128, 0, stream>>>(part_src, stats);
  k_embed1<<<dim3(4, 32), 256, 0, stream>>>(awB, peB, pe_b1, hid);
  k_embed2<<<4096, 64, 0, stream>>>(hid, pe_w2, pe_b2, emb);
  k_curstats<<<4, 256, 0, stream>>>(emb, stats);
  k_gatt<<<dim3(4, 16), 256, 0, stream>>>(emb, aalpha, abeta, attB);
  k_rowsum<<<1024, 256, 0, stream>>>(attB, rowsum);
  k_rw<<<dim3(48, 8, 4), 256, 0, stream>>>(attB, awT, rowsum, stats, rw);
  k_dwconv<true><<<dim3(4, 64, 384), dim3(64, 4), 0, stream>>>(X, hf_w1, hf_b1, hf1);
  k_dwconv<false><<<dim3(4, 64, 384), dim3(64, 4), 0, stream>>>(hf1, hf_w2, hf_b2, hf);
  k_fs<<<NWINS, 256, 0, stream>>>(rw, hf, fs);
  k_conv1<<<dim3(2, 32, 24), dim3(64, 4), 0, stream>>>(fs, fus_w1, c1);
  k_conv2pool<<<dim3(4, 12, 8), 256, 0, stream>>>(c1, fus_w2, part_pool);
  k_gate<<<4, 128, 0, stream>>>(part_pool, gate);
  k_final<<<2048, 256, 0, stream>>>(fs, gate, (float*)d_out);
}

// Round 3
// 1544.954 us; speedup vs baseline: 1.7633x; 1.2297x over previous
//
#include <hip/hip_runtime.h>

// ---------------- constants ----------------
constexpr int B_ = 4, C_ = 96, H_ = 256, W_ = 256;
constexpr int NWINS = 4096;              // B*nh*nw
constexpr float EPSG = 1e-8f;
constexpr float ATT_Ac = 30.f, ATT_Bc = 20.f;
constexpr float QSCALE = 0.17677669529663687f;  // 32^-0.5
constexpr long long BIG = (long long)B_ * C_ * H_ * W_;  // 25165824

typedef unsigned short u16;
typedef unsigned int u32;
typedef __attribute__((ext_vector_type(8))) __bf16 bf16x8;
typedef __attribute__((ext_vector_type(4))) float f32x4;

#define AS(n) __attribute__((address_space(n)))

__device__ __forceinline__ void gload16(const void* g, void* l) {
  __builtin_amdgcn_global_load_lds((AS(1) void*)g, (AS(3) void*)l, 16, 0, 0);
}

__device__ __forceinline__ u16 f2b(float f) {
  union { float f; u32 i; } x; x.f = f;
  u32 r = (x.i + 0x7fffu + ((x.i >> 16) & 1u)) >> 16;
  return (u16)r;
}
__device__ __forceinline__ float blo(u32 u) { union { u32 i; float f; } x; x.i = u << 16; return x.f; }
__device__ __forceinline__ float bhi(u32 u) { union { u32 i; float f; } x; x.i = u & 0xffff0000u; return x.f; }
__device__ __forceinline__ __bf16 f2bf(float f) { union { u16 u; __bf16 b; } c; c.u = f2b(f); return c.b; }

// ---------------- weight prep: fragment-linear qkv weights + bias ----------------
// wfrag[(ot*3+ks)*512 + l*8 + j] = W[ot*16+(l&15)][ks*32+(l>>4)*8+j]
__global__ void k_wt2(const float* __restrict__ lfqk_w, const float* __restrict__ lfqk_b,
                      const float* __restrict__ lfv_w, const float* __restrict__ lfv_b,
                      u16* __restrict__ wfrag, float* __restrict__ bq) {
  int t = blockIdx.x * 256 + threadIdx.x;   // 108 blocks -> 27648
  if (t < 27648) {
    int ot = t / 1536, r1 = t % 1536;
    int ks = r1 / 512, q = r1 % 512;
    int l = q >> 3, j = q & 7;
    int oc = ot * 16 + (l & 15);
    int ic = ks * 32 + (l >> 4) * 8 + j;
    float wv = (oc < 192) ? lfqk_w[oc * 96 + ic] : lfv_w[(oc - 192) * 96 + ic];
    wfrag[t] = f2b(wv);
  }
  if (t < 288) bq[t] = (t < 192) ? lfqk_b[t] : lfv_b[t - 192];
}

// ---------------- relative-position bias MLP ----------------
__global__ void k_bias(const float* __restrict__ w1, const float* __restrict__ b1,
                       const float* __restrict__ w2, const float* __restrict__ b2,
                       float* __restrict__ bias) {
  int t = blockIdx.x * 256 + threadIdx.x;
  if (t >= 4096) return;
  int n = t >> 6, m = t & 63;
  float dy = (float)((n >> 3) - (m >> 3));
  float dx = (float)((n & 7) - (m & 7));
  float fy = (dy > 0.f ? 1.f : (dy < 0.f ? -1.f : 0.f)) * log1pf(fabsf(dy));
  float fx = (dx > 0.f ? 1.f : (dx < 0.f ? -1.f : 0.f)) * log1pf(fabsf(dx));
  float o0 = b2[0], o1 = b2[1], o2 = b2[2];
  for (int j = 0; j < 256; ++j) {
    float h = fmaxf(w1[2 * j] * fy + w1[2 * j + 1] * fx + b1[j], 0.f);
    o0 += w2[j] * h; o1 += w2[256 + j] * h; o2 += w2[512 + j] * h;
  }
  bias[t] = o0; bias[4096 + t] = o1; bias[8192 + t] = o2;
}

// ---------------- fp32 -> bf16 convert (pe_w1) ----------------
__global__ void k_cvtw(const float* __restrict__ in, u16* __restrict__ out, int n) {
  int i = (blockIdx.x * 256 + threadIdx.x) * 4;
  if (i < n) {
    float4 v = *(const float4*)(in + i);
    out[i] = f2b(v.x); out[i + 1] = f2b(v.y); out[i + 2] = f2b(v.z); out[i + 3] = f2b(v.w);
  }
}

// ---------------- fused qkv conv + window attention (MFMA) ----------------
// one block per window; waves 0..3 each own a 16-pixel column tile for qkv;
// waves 0..2 then each own one head for attention.
__global__ __launch_bounds__(256) void k_front(const float* __restrict__ X,
                       const u16* __restrict__ wfrag, const float* __restrict__ bqv,
                       const float* __restrict__ bias_tab, u16* __restrict__ awB) {
  // per head: bytes [0,4096) = Q[p][d] (swz), [4096,8192) = K[p][d] (swz);
  // later overlaid by P[q][kp] (swz, 128B rows)
  __shared__ u16 uni[3][4096];
  __shared__ u16 vt[3][2048];   // per head: Vt[d][p] 32x64 (swz, 128B rows)
  int win = blockIdx.x;
  int b = win >> 10, wy = (win >> 5) & 31, wx = win & 31;
  int t = threadIdx.x;
  int w = t >> 6, l = t & 63;
  int lr = l & 15, lg = l >> 4;
  // ---- phase 0: X B-fragments straight from global ----
  int p = w * 16 + lr;                       // this lane's pixel (window order)
  const float* Xp = X + (long long)b * 96 * 65536 + (wy * 8 + (p >> 3)) * 256 + wx * 8 + (p & 7);
  bf16x8 xf[3];
#pragma unroll
  for (int ks = 0; ks < 3; ++ks)
#pragma unroll
    for (int j = 0; j < 8; ++j)
      xf[ks][j] = f2bf(Xp[(ks * 32 + lg * 8 + j) * 65536]);
  // ---- phase 1: qkv GEMM, D[oc][p] ----
  f32x4 acc[18];
  f32x4 z = {0.f, 0.f, 0.f, 0.f};
#pragma unroll
  for (int ot = 0; ot < 18; ++ot) acc[ot] = z;
#pragma unroll
  for (int ks = 0; ks < 3; ++ks)
#pragma unroll
    for (int ot = 0; ot < 18; ++ot) {
      bf16x8 af = *(const bf16x8*)(wfrag + ((ot * 3 + ks) * 64 + l) * 8);
      acc[ot] = __builtin_amdgcn_mfma_f32_16x16x32_bf16(af, xf[ks], acc[ot], 0, 0, 0);
    }
  // ---- phase 2: bias/scale, store Q,K,Vt to LDS (bf16, swizzled) ----
#pragma unroll
  for (int ot = 0; ot < 18; ++ot) {
#pragma unroll
    for (int r = 0; r < 4; ++r) {
      int oc = ot * 16 + lg * 4 + r;
      float vv = acc[ot][r] + bqv[oc];
      int s3 = ot / 6;                       // 0=Q 1=K 2=V (uniform per ot)
      int cc = oc - s3 * 96, h = cc >> 5, d = cc & 31;
      if (s3 == 0) vv *= QSCALE;
      u16 bv = f2b(vv);
      if (s3 < 2) {
        int byo = s3 * 4096 + (((p * 64 + 2 * d) ^ ((p & 3) << 4)));
        *(u16*)((char*)uni[h] + byo) = bv;
      } else {
        int byo = (d * 128 + 2 * p) ^ ((d & 7) << 4);
        *(u16*)((char*)vt[h] + byo) = bv;
      }
    }
  }
  __syncthreads();
  // ---- phase 3: attention, wave h = head h ----
  if (w < 3) {
    int h = w;
    bf16x8 qf[4], kf[4];
#pragma unroll
    for (int qt = 0; qt < 4; ++qt) {
      int row = qt * 16 + lr;
      qf[qt] = *(const bf16x8*)((char*)uni[h] + (((row * 64 + lg * 16) ^ ((row & 3) << 4))));
      kf[qt] = *(const bf16x8*)((char*)uni[h] + 4096 + (((row * 64 + lg * 16) ^ ((row & 3) << 4))));
    }
    f32x4 s[4][4];
#pragma unroll
    for (int qt = 0; qt < 4; ++qt)
#pragma unroll
      for (int kt = 0; kt < 4; ++kt)
        s[qt][kt] = __builtin_amdgcn_mfma_f32_16x16x32_bf16(qf[qt], kf[kt], z, 0, 0, 0);
    const float* bt = bias_tab + h * 4096;
#pragma unroll
    for (int qt = 0; qt < 4; ++qt)
#pragma unroll
      for (int r = 0; r < 4; ++r) {
        int n = qt * 16 + lg * 4 + r;
#pragma unroll
        for (int kt = 0; kt < 4; ++kt)
          s[qt][kt][r] += bt[n * 64 + kt * 16 + lr];
      }
    // softmax rows: reduce over kt (regs) then lanes 0..15 of each 16-group
#pragma unroll
    for (int qt = 0; qt < 4; ++qt)
#pragma unroll
      for (int r = 0; r < 4; ++r) {
        float m = fmaxf(fmaxf(s[qt][0][r], s[qt][1][r]), fmaxf(s[qt][2][r], s[qt][3][r]));
        m = fmaxf(m, __shfl_xor(m, 1)); m = fmaxf(m, __shfl_xor(m, 2));
        m = fmaxf(m, __shfl_xor(m, 4)); m = fmaxf(m, __shfl_xor(m, 8));
        float sum = 0.f;
#pragma unroll
        for (int kt = 0; kt < 4; ++kt) {
          float e = __expf(s[qt][kt][r] - m);
          s[qt][kt][r] = e; sum += e;
        }
        sum += __shfl_xor(sum, 1); sum += __shfl_xor(sum, 2);
        sum += __shfl_xor(sum, 4); sum += __shfl_xor(sum, 8);
        float inv = 1.f / sum;
        int q = qt * 16 + lg * 4 + r;
#pragma unroll
        for (int kt = 0; kt < 4; ++kt) {
          int kp = kt * 16 + lr;
          int byo = (q * 128 + 2 * kp) ^ ((q & 7) << 4);
          *(u16*)((char*)uni[h] + byo) = f2b(s[qt][kt][r] * inv);
        }
      }
    // PV: out[q][d] = P[q][kp] · Vt[d][kp]
    f32x4 o[4][2];
#pragma unroll
    for (int qt = 0; qt < 4; ++qt) { o[qt][0] = z; o[qt][1] = z; }
#pragma unroll
    for (int kv = 0; kv < 2; ++kv) {
      bf16x8 ap[4], bv[2];
#pragma unroll
      for (int qt = 0; qt < 4; ++qt) {
        int q = qt * 16 + lr;
        ap[qt] = *(const bf16x8*)((char*)uni[h] + (((q * 128 + kv * 64 + lg * 16) ^ ((q & 7) << 4))));
      }
#pragma unroll
      for (int dt = 0; dt < 2; ++dt) {
        int d = dt * 16 + lr;
        bv[dt] = *(const bf16x8*)((char*)vt[h] + (((d * 128 + kv * 64 + lg * 16) ^ ((d & 7) << 4))));
      }
#pragma unroll
      for (int qt = 0; qt < 4; ++qt)
#pragma unroll
        for (int dt = 0; dt < 2; ++dt)
          o[qt][dt] = __builtin_amdgcn_mfma_f32_16x16x32_bf16(ap[qt], bv[dt], o[qt][dt], 0, 0, 0);
    }
    u16* ob = awB + (long long)win * 6144;
#pragma unroll
    for (int qt = 0; qt < 4; ++qt)
#pragma unroll
      for (int dt = 0; dt < 2; ++dt)
#pragma unroll
        for (int r = 0; r < 4; ++r) {
          int q = qt * 16 + lg * 4 + r;
          int c = h * 32 + dt * 16 + lr;
          ob[q * 96 + c] = f2b(o[qt][dt][r]);
        }
  }
}

// ---------------- transpose awB [b][p][f] -> awT [b][f][p] (bf16) ----------------
__global__ __launch_bounds__(256) void k_awT(const u16* __restrict__ awB, u16* __restrict__ awT) {
  __shared__ u16 tile[64][80];
  int f0 = blockIdx.x * 64, p0 = blockIdx.y * 64, b = blockIdx.z;
  int t = threadIdx.x;
  const u16* src = awB + ((long long)b * 1024 + p0) * 6144 + f0;
  int pr = t >> 2, fc = (t & 3) * 16;
  uint4 v0 = *(const uint4*)(src + (long long)pr * 6144 + fc);
  uint4 v1 = *(const uint4*)(src + (long long)pr * 6144 + fc + 8);
  u16 e[16];
  *(uint4*)&e[0] = v0; *(uint4*)&e[8] = v1;
#pragma unroll
  for (int j = 0; j < 16; ++j) tile[fc + j][pr] = e[j];
  __syncthreads();
  int fr = t >> 2, pc = (t & 3) * 16;
  u16* dst = awT + ((long long)b * 6144 + f0 + fr) * 1024 + p0 + pc;
  *(uint4*)(dst) = *(const uint4*)&tile[fr][pc];
  *(uint4*)(dst + 8) = *(const uint4*)&tile[fr][pc + 8];
}

// ---------------- src stats from awB (bf16) ----------------
__global__ void k_redA(const u16* __restrict__ awB, float* __restrict__ part) {
  int b = blockIdx.x, blk = blockIdx.y, t = threadIdx.x;
  const uint4* p = (const uint4*)(awB + (long long)b * 6291456 + (long long)blk * 49152);
  float s = 0.f, ss = 0.f;
  for (int i = t; i < 6144; i += 256) {
    uint4 x = p[i];
    u32 w[4] = {x.x, x.y, x.z, x.w};
#pragma unroll
    for (int j = 0; j < 4; ++j) {
      float a = blo(w[j]), c = bhi(w[j]);
      s += a + c; ss += a * a + c * c;
    }
  }
  __shared__ float r1[256], r2[256];
  r1[t] = s; r2[t] = ss; __syncthreads();
  for (int st = 128; st; st >>= 1) {
    if (t < st) { r1[t] += r1[t + st]; r2[t] += r2[t + st]; }
    __syncthreads();
  }
  if (t == 0) { part[(b * 128 + blk) * 2] = r1[0]; part[(b * 128 + blk) * 2 + 1] = r2[0]; }
}

__global__ void k_redB(const float* __restrict__ part, float* __restrict__ stats) {
  int b = blockIdx.x, t = threadIdx.x;
  float s = part[(b * 128 + t) * 2], ss = part[(b * 128 + t) * 2 + 1];
  __shared__ float r1[128], r2[128];
  r1[t] = s; r2[t] = ss; __syncthreads();
  for (int st = 64; st; st >>= 1) {
    if (t < st) { r1[t] += r1[t + st]; r2[t] += r2[t + st]; }
    __syncthreads();
  }
  if (t == 0) {
    float n = 6291456.f, m = r1[0] / n;
    stats[b] = m;
    stats[4 + b] = sqrtf(fmaxf(r2[0] / n - m * m, 0.f) + EPSG);
  }
}

// ---------------- patch-embed GEMM (MFMA): hid = relu(awB @ peB^T + b1) ----------------
__global__ __launch_bounds__(256) void k_embed1(const u16* __restrict__ awB, const u16* __restrict__ peB,
                         const float* __restrict__ b1, float* __restrict__ hid) {
  __shared__ __align__(16) u16 As[128 * 32];
  __shared__ __align__(16) u16 Bs[64 * 32];
  int n0 = blockIdx.x * 64, m0 = blockIdx.y * 128;
  int t = threadIdx.x;
  const u16* Ag = awB + (long long)m0 * 6144;
  const u16* Bg = peB + (long long)n0 * 6144;
  f32x4 acc[4][2];
  f32x4 z = {0.f, 0.f, 0.f, 0.f};
#pragma unroll
  for (int i = 0; i < 4; ++i) { acc[i][0] = z; acc[i][1] = z; }
  int w = t >> 6, l = t & 63;
  int wm = (w >> 1) * 64, wn = (w & 1) * 32;
  int ro = l & 15, ko = (l >> 4) * 16;
  for (int k0 = 0; k0 < 6144; k0 += 32) {
#pragma unroll
    for (int i = 0; i < 2; ++i) {
      int c = t + 256 * i;
      gload16(Ag + (long long)(c >> 2) * 6144 + k0 + (c & 3) * 8, (char*)As + c * 16);
    }
    gload16(Bg + (long long)(t >> 2) * 6144 + k0 + (t & 3) * 8, (char*)Bs + t * 16);
    __syncthreads();
    bf16x8 a[4], bb[2];
#pragma unroll
    for (int fm = 0; fm < 4; ++fm)
      a[fm] = *(const bf16x8*)((const char*)As + (wm + fm * 16 + ro) * 64 + ko);
#pragma unroll
    for (int fn = 0; fn < 2; ++fn)
      bb[fn] = *(const bf16x8*)((const char*)Bs + (wn + fn * 16 + ro) * 64 + ko);
#pragma unroll
    for (int fm = 0; fm < 4; ++fm)
#pragma unroll
      for (int fn = 0; fn < 2; ++fn)
        acc[fm][fn] = __builtin_amdgcn_mfma_f32_16x16x32_bf16(a[fm], bb[fn], acc[fm][fn], 0, 0, 0);
    __syncthreads();
  }
#pragma unroll
  for (int fm = 0; fm < 4; ++fm)
#pragma unroll
    for (int r = 0; r < 4; ++r) {
      int m = m0 + wm + fm * 16 + (l >> 4) * 4 + r;
#pragma unroll
      for (int fn = 0; fn < 2; ++fn) {
        int n = n0 + wn + fn * 16 + (l & 15);
        hid[(long long)m * 256 + n] = fmaxf(acc[fm][fn][r] + b1[n], 0.f);
      }
    }
}

// ---------------- embed stage 2 + l2 norm ----------------
__global__ __launch_bounds__(64) void k_embed2(const float* __restrict__ hid, const float* __restrict__ w2,
                        const float* __restrict__ b2, float* __restrict__ emb) {
  __shared__ float hrow[256];
  int pa = blockIdx.x, t = threadIdx.x;
  const float* hp = hid + (long long)pa * 256;
  for (int i = t; i < 256; i += 64) hrow[i] = hp[i];
  __syncthreads();
  float acc = 0.f;
  if (t < 30) {
    acc = b2[t];
    const float* wp = w2 + t * 256;
    for (int j = 0; j < 256; ++j) acc += wp[j] * hrow[j];
  }
  float sq = (t < 30) ? acc * acc : 0.f;
  for (int off = 32; off; off >>= 1) sq += __shfl_down(sq, off);
  float ss = __shfl(sq, 0);
  float scale = 1.f / (sqrtf(ss) + EPSG);
  if (t < 30) emb[(long long)pa * 30 + t] = acc * scale;
}

// ---------------- cur stats over emb per batch ----------------
__global__ void k_curstats(const float* __restrict__ emb, float* __restrict__ stats) {
  int b = blockIdx.x, t = threadIdx.x;
  const float* p = emb + (long long)b * 30720;
  float s = 0.f, ss = 0.f;
  for (int i = t; i < 30720; i += 256) { float x = p[i]; s += x; ss += x * x; }
  __shared__ float r1[256], r2[256];
  r1[t] = s; r2[t] = ss; __syncthreads();
  for (int st = 128; st; st >>= 1) {
    if (t < st) { r1[t] += r1[t + st]; r2[t] += r2[t + st]; }
    __syncthreads();
  }
  if (t == 0) {
    float n = 30720.f, m = r1[0] / n;
    stats[8 + b] = m;
    stats[12 + b] = sqrtf(fmaxf(r2[0] / n - m * m, 0.f) + EPSG);
  }
}

// ---------------- global-attention exp scores -> bf16 ----------------
__global__ void k_gatt(const float* __restrict__ emb, const float* __restrict__ alpha,
                       const float* __restrict__ beta, u16* __restrict__ attB) {
  __shared__ float er[64][33];
  __shared__ float ec[64][33];
  int b = blockIdx.x, r0 = blockIdx.y * 64, t = threadIdx.x;
  const float* eb = emb + (long long)b * 30720;
  for (int f = t; f < 1920; f += 256) er[f / 30][f % 30] = eb[(r0 + f / 30) * 30 + f % 30];
  float ca = ATT_Ac * alpha[0], cb = ATT_Bc * beta[0];
  int lane = t & 63, w = t >> 6;
  for (int c0 = 0; c0 < 1024; c0 += 64) {
    __syncthreads();
    for (int f = t; f < 1920; f += 256) ec[f / 30][f % 30] = eb[(c0 + f / 30) * 30 + f % 30];
    __syncthreads();
    for (int rr = w; rr < 64; rr += 4) {
      float acc = 0.f;
#pragma unroll
      for (int d = 0; d < 30; ++d) acc += er[rr][d] * ec[lane][d];
      attB[((long long)b * 1024 + r0 + rr) * 1024 + c0 + lane] = f2b(__expf(ca * acc + cb));
    }
  }
}

// ---------------- row sums of attB ----------------
__global__ void k_rowsum(const u16* __restrict__ attB, float* __restrict__ rowsum) {
  int row = blockIdx.x * 4 + (threadIdx.x >> 6);
  int lane = threadIdx.x & 63;
  const uint4* p = (const uint4*)(attB + (long long)row * 1024);
  float s = 0.f;
  for (int i = lane; i < 128; i += 64) {
    uint4 x = p[i];
    s += blo(x.x) + bhi(x.x) + blo(x.y) + bhi(x.y) + blo(x.z) + bhi(x.z) + blo(x.w) + bhi(x.w);
  }
  for (int off = 32; off; off >>= 1) s += __shfl_down(s, off);
  if (lane == 0) rowsum[row] = s;
}

// ---------------- rw GEMM (MFMA, B^T form) + AdaIN epilogue ----------------
__global__ __launch_bounds__(256) void k_rw(const u16* __restrict__ attB, const u16* __restrict__ x4T,
                     const float* __restrict__ rowsum, const float* __restrict__ stats,
                     float* __restrict__ rw) {
  __shared__ __align__(16) u16 As[128 * 32];
  __shared__ __align__(16) u16 Bs[128 * 32];
  int b = blockIdx.z;
  int n0 = blockIdx.x * 128, m0 = blockIdx.y * 128;
  const u16* Ag = attB + ((long long)b * 1024 + m0) * 1024;
  const u16* Bg = x4T + ((long long)b * 6144 + n0) * 1024;
  int t = threadIdx.x;
  f32x4 acc[4][4];
  f32x4 z = {0.f, 0.f, 0.f, 0.f};
#pragma unroll
  for (int i = 0; i < 4; ++i)
#pragma unroll
    for (int j = 0; j < 4; ++j) acc[i][j] = z;
  int w = t >> 6, l = t & 63;
  int wm = (w >> 1) * 64, wn = (w & 1) * 64;
  int ro = l & 15, ko = (l >> 4) * 16;
  for (int k0 = 0; k0 < 1024; k0 += 32) {
#pragma unroll
    for (int i = 0; i < 2; ++i) {
      int c = t + 256 * i;
      gload16(Ag + (c >> 2) * 1024 + k0 + (c & 3) * 8, (char*)As + c * 16);
      gload16(Bg + (c >> 2) * 1024 + k0 + (c & 3) * 8, (char*)Bs + c * 16);
    }
    __syncthreads();
    bf16x8 a[4], bb[4];
#pragma unroll
    for (int fm = 0; fm < 4; ++fm)
      a[fm] = *(const bf16x8*)((const char*)As + (wm + fm * 16 + ro) * 64 + ko);
#pragma unroll
    for (int fn = 0; fn < 4; ++fn)
      bb[fn] = *(const bf16x8*)((const char*)Bs + (wn + fn * 16 + ro) * 64 + ko);
#pragma unroll
    for (int fm = 0; fm < 4; ++fm)
#pragma unroll
      for (int fn = 0; fn < 4; ++fn)
        acc[fm][fn] = __builtin_amdgcn_mfma_f32_16x16x32_bf16(a[fm], bb[fn], acc[fm][fn], 0, 0, 0);
    __syncthreads();
  }
  float sm = stats[b], ssd = stats[4 + b], cm = stats[8 + b], inv_cs = 1.f / stats[12 + b];
#pragma unroll
  for (int fm = 0; fm < 4; ++fm)
#pragma unroll
    for (int r = 0; r < 4; ++r) {
      int m = m0 + wm + fm * 16 + (l >> 4) * 4 + r;
      float sc = 1.f / (rowsum[b * 1024 + m] + EPSG);
      float* dst = rw + ((long long)b * 1024 + m) * 6144 + n0 + wn + (l & 15);
#pragma unroll
      for (int fn = 0; fn < 4; ++fn) {
        float val = acc[fm][fn][r] * sc;
        dst[fn * 16] = (val - cm) * inv_cs * ssd + sm;
      }
    }
}

// ---------------- depthwise 5x5 conv, reflect pad ----------------
template <bool RELU>
__global__ void k_dwconv(const float* __restrict__ in, const float* __restrict__ w,
                         const float* __restrict__ bias, float* __restrict__ out) {
  int x = blockIdx.x * 64 + threadIdx.x;
  int y = blockIdx.y * 4 + threadIdx.y;
  int bc = blockIdx.z, c = bc % 96;
  const float* ip = in + (long long)bc * 65536;
  const float* wp = w + c * 25;
  float acc = bias[c];
#pragma unroll
  for (int ky = 0; ky < 5; ++ky) {
    int iy = y + ky - 2;
    iy = iy < 0 ? -iy : (iy > 255 ? 510 - iy : iy);
    const float* row = ip + iy * 256;
#pragma unroll
    for (int kx = 0; kx < 5; ++kx) {
      int ix = x + kx - 2;
      ix = ix < 0 ? -ix : (ix > 255 ? 510 - ix : ix);
      acc += wp[ky * 5 + kx] * row[ix];
    }
  }
  out[(long long)bc * 65536 + y * 256 + x] = RELU ? fmaxf(acc, 0.f) : acc;
}

// ---------------- window reverse + add hf -> feats_sum ----------------
__global__ void k_fs(const float* __restrict__ rw, const float* __restrict__ hf,
                     float* __restrict__ fs) {
  __shared__ float tile[64 * 97];
  int win = blockIdx.x;
  int b = win >> 10, wy = (win >> 5) & 31, wx = win & 31;
  int t = threadIdx.x;
  const float* src = rw + (long long)win * 6144;
  for (int f = t; f < 6144; f += 256) tile[(f / 96) * 97 + f % 96] = src[f];
  __syncthreads();
  long long obase = (long long)b * 96 * 65536;
  for (int f = t; f < 6144; f += 256) {
    int c = f >> 6, p = f & 63;
    long long oidx = obase + (long long)c * 65536 + (wy * 8 + (p >> 3)) * 256 + wx * 8 + (p & 7);
    fs[oidx] = tile[p * 97 + c] + hf[oidx];
  }
}

// ---------------- SKFusion conv1 3x3 s2 p1 + relu ----------------
__global__ void k_conv1(const float* __restrict__ fs, const float* __restrict__ w,
                        float* __restrict__ out) {
  int ox = blockIdx.x * 64 + threadIdx.x;
  int oy = blockIdx.y * 4 + threadIdx.y;
  int z = blockIdx.z, b = z / 6, og = z % 6, oc0 = og * 8;
  const float* ip = fs + (long long)b * 96 * 65536;
  float acc[8] = {};
  for (int ic = 0; ic < 96; ++ic) {
    const float* plane = ip + (long long)ic * 65536;
    float xv[3][3];
#pragma unroll
    for (int ky = 0; ky < 3; ++ky) {
      int iy = 2 * oy + ky - 1;
#pragma unroll
      for (int kx = 0; kx < 3; ++kx) {
        int ix = 2 * ox + kx - 1;
        xv[ky][kx] = (iy >= 0 && iy < 256 && ix >= 0 && ix < 256) ? plane[iy * 256 + ix] : 0.f;
      }
    }
#pragma unroll
    for (int o = 0; o < 8; ++o) {
      const float* wp = w + ((oc0 + o) * 96 + ic) * 9;
      acc[o] += wp[0] * xv[0][0] + wp[1] * xv[0][1] + wp[2] * xv[0][2]
              + wp[3] * xv[1][0] + wp[4] * xv[1][1] + wp[5] * xv[1][2]
              + wp[6] * xv[2][0] + wp[7] * xv[2][1] + wp[8] * xv[2][2];
    }
  }
#pragma unroll
  for (int o = 0; o < 8; ++o)
    out[(((long long)b * 48 + oc0 + o) * 128 + oy) * 128 + ox] = fmaxf(acc[o], 0.f);
}

// ---------------- SKFusion conv2 3x3 s2 p1 + partial pooling ----------------
__global__ void k_conv2pool(const float* __restrict__ c1, const float* __restrict__ w,
                            float* __restrict__ part) {
  int b = blockIdx.x, og = blockIdx.y, split = blockIdx.z, oc0 = og * 8;
  int t = threadIdx.x;
  const float* ip = c1 + (long long)b * 48 * 16384;
  float acc[8] = {};
  for (int pi = 0; pi < 2; ++pi) {
    int p = split * 512 + pi * 256 + t;
    int oy = p >> 6, ox = p & 63;
    for (int ic = 0; ic < 48; ++ic) {
      const float* plane = ip + ic * 16384;
      float xv[3][3];
#pragma unroll
      for (int ky = 0; ky < 3; ++ky) {
        int iy = 2 * oy + ky - 1;
#pragma unroll
        for (int kx = 0; kx < 3; ++kx) {
          int ix = 2 * ox + kx - 1;
          xv[ky][kx] = (iy >= 0 && iy < 128 && ix >= 0 && ix < 128) ? plane[iy * 128 + ix] : 0.f;
        }
      }
#pragma unroll
      for (int o = 0; o < 8; ++o) {
        const float* wp = w + ((oc0 + o) * 48 + ic) * 9;
        acc[o] += wp[0] * xv[0][0] + wp[1] * xv[0][1] + wp[2] * xv[0][2]
                + wp[3] * xv[1][0] + wp[4] * xv[1][1] + wp[5] * xv[1][2]
                + wp[6] * xv[2][0] + wp[7] * xv[2][1] + wp[8] * xv[2][2];
      }
    }
  }
  __shared__ float red[256];
  for (int o = 0; o < 8; ++o) {
    red[t] = acc[o]; __syncthreads();
    for (int st = 128; st; st >>= 1) {
      if (t < st) red[t] += red[t + st];
      __syncthreads();
    }
    if (t == 0) part[((b * 12 + og) * 8 + split) * 8 + o] = red[0];
    __syncthreads();
  }
}

// ---------------- gate: reduce partials + channel softmax ----------------
__global__ void k_gate(const float* __restrict__ part, float* __restrict__ gate) {
  int b = blockIdx.x, t = threadIdx.x;
  __shared__ float val[96];
  __shared__ float red[128];
  if (t < 96) {
    int og = t / 8, o = t % 8;
    float s = 0.f;
    for (int sp = 0; sp < 8; ++sp) s += part[((b * 12 + og) * 8 + sp) * 8 + o];
    val[t] = s / 4096.f;
  }
  __syncthreads();
  float m = (t < 96) ? val[t] : -1e30f;
  red[t] = m; __syncthreads();
  for (int st = 64; st; st >>= 1) { if (t < st) red[t] = fmaxf(red[t], red[t + st]); __syncthreads(); }
  float mx = red[0]; __syncthreads();
  float e = (t < 96) ? __expf(val[t] - mx) : 0.f;
  red[t] = e; __syncthreads();
  for (int st = 64; st; st >>= 1) { if (t < st) red[t] += red[t + st]; __syncthreads(); }
  if (t < 96) gate[b * 96 + t] = e / red[0];
}

// ---------------- final: out = feats_sum * gate[b,c] ----------------
__global__ void k_final(const float* __restrict__ fs, const float* __restrict__ gate,
                        float* __restrict__ out) {
  long long i0 = ((long long)blockIdx.x * 256 + threadIdx.x) * 4;
  long long stride = (long long)gridDim.x * 1024;
  for (long long i = i0; i < 25165824LL; i += stride) {
    float4 x = *(const float4*)(fs + i);
    float g = gate[(int)(i >> 16)];
    x.x *= g; x.y *= g; x.z *= g; x.w *= g;
    *(float4*)(out + i) = x;
  }
}

// ---------------- launch ----------------
extern "C" void kernel_launch(void* const* d_in, const int* in_sizes, int n_in,
                              void* d_out, int out_size, void* d_ws, size_t ws_size,
                              hipStream_t stream) {
  const float* X      = (const float*)d_in[0];
  const float* hf_w1  = (const float*)d_in[1];
  const float* hf_b1  = (const float*)d_in[2];
  const float* hf_w2  = (const float*)d_in[3];
  const float* hf_b2  = (const float*)d_in[4];
  const float* lfv_w  = (const float*)d_in[5];
  const float* lfv_b  = (const float*)d_in[6];
  const float* lfqk_w = (const float*)d_in[7];
  const float* lfqk_b = (const float*)d_in[8];
  const float* mw1    = (const float*)d_in[9];
  const float* mb1    = (const float*)d_in[10];
  const float* mw2    = (const float*)d_in[11];
  const float* mb2    = (const float*)d_in[12];
  const float* pe_w1  = (const float*)d_in[13];
  const float* pe_b1  = (const float*)d_in[14];
  const float* pe_w2  = (const float*)d_in[15];
  const float* pe_b2  = (const float*)d_in[16];
  const float* aalpha = (const float*)d_in[17];
  const float* abeta  = (const float*)d_in[18];
  const float* fus_w1 = (const float*)d_in[19];
  const float* fus_w2 = (const float*)d_in[20];

  float* W = (float*)d_ws;
  float* rw  = W;                        // BIG
  float* hf1 = W + BIG;                  // BIG
  u16* awB = (u16*)(W + 2 * BIG);        // BIG bf16
  u16* awT = awB + BIG;                  // BIG bf16
  float* fs  = W + 2 * BIG;              // alias awB+awT (dead after k_rw)
  float* SM = W + 3 * BIG;
  float* bias_tab  = SM;                 // 12288
  u16*   wfrag     = (u16*)(SM + 12288); // 27648 u16
  float* bqv       = SM + 26112;         // 288
  float* hid       = SM + 26400;         // 1048576
  float* emb       = SM + 1074976;       // 122880
  u16*   attB      = (u16*)(SM + 1197856);   // 4194304 u16
  float* rowsum    = SM + 3295008;       // 4096
  float* part_src  = SM + 3299104;       // 1024
  float* stats     = SM + 3300128;       // 16
  float* part_pool = SM + 3300144;       // 3072
  float* gate      = SM + 3303216;       // 384
  float* c1        = SM + 3303600;       // 3145728
  u16*   peB       = (u16*)(SM + 6449328);   // 1572864 u16
  float* hf = (float*)d_out;             // hf aliases d_out

  k_wt2<<<108, 256, 0, stream>>>(lfqk_w, lfqk_b, lfv_w, lfv_b, wfrag, bqv);
  k_bias<<<16, 256, 0, stream>>>(mw1, mb1, mw2, mb2, bias_tab);
  k_cvtw<<<1536, 256, 0, stream>>>(pe_w1, peB, 256 * 6144);
  k_front<<<NWINS, 256, 0, stream>>>(X, wfrag, bqv, bias_tab, awB);
  k_awT<<<dim3(96, 16, 4), 256, 0, stream>>>(awB, awT);
  k_redA<<<dim3(4, 128), 256, 0, stream>>>(awB, part_src);
  k_redB<<<4, 128, 0, stream>>>(part_src, stats);
  k_embed1<<<dim3(4, 32), 256, 0, stream>>>(awB, peB, pe_b1, hid);
  k_embed2<<<4096, 64, 0, stream>>>(hid, pe_w2, pe_b2, emb);
  k_curstats<<<4, 256, 0, stream>>>(emb, stats);
  k_gatt<<<dim3(4, 16), 256, 0, stream>>>(emb, aalpha, abeta, attB);
  k_rowsum<<<1024, 256, 0, stream>>>(attB, rowsum);
  k_rw<<<dim3(48, 8, 4), 256, 0, stream>>>(attB, awT, rowsum, stats, rw);
  k_dwconv<true><<<dim3(4, 64, 384), dim3(64, 4), 0, stream>>>(X, hf_w1, hf_b1, hf1);
  k_dwconv<false><<<dim3(4, 64, 384), dim3(64, 4), 0, stream>>>(hf1, hf_w2, hf_b2, hf);
  k_fs<<<NWINS, 256, 0, stream>>>(rw, hf, fs);
  k_conv1<<<dim3(2, 32, 24), dim3(64, 4), 0, stream>>>(fs, fus_w1, c1);
  k_conv2pool<<<dim3(4, 12, 8), 256, 0, stream>>>(c1, fus_w2, part_pool);
  k_gate<<<4, 128, 0, stream>>>(part_pool, gate);
  k_final<<<2048, 256, 0, stream>>>(fs, gate, (float*)d_out);
}